// Round 3
// baseline (281.055 us; speedup 1.0000x reference)
//
#include <hip/hip_runtime.h>
#include <cstddef>
#include <cstdint>

#define LRELU(v) ((v) > 0.f ? (v) : 0.2f * (v))

// ---------------- CSR build ----------------

__global__ void k_deg_init(int* deg, int N) {
    int i = blockIdx.x * blockDim.x + threadIdx.x;
    if (i < N) deg[i] = 1;  // self-loop
}

__global__ void k_hist(const int* src, const int* dst, int* deg, int E) {
    int e = blockIdx.x * blockDim.x + threadIdx.x;
    if (e < E) {
        int s = src[e], d = dst[e];
        if (s != d) atomicAdd(&deg[d], 1);  // masked self-edges dropped
    }
}

__global__ __launch_bounds__(1024) void k_scan(const int* deg, int* offs, int* cursor, int N) {
    __shared__ int part[1024];
    int t = threadIdx.x;
    int chunk = (N + 1023) >> 10;
    int start = t * chunk;
    int s = 0;
    for (int i = 0; i < chunk; i++) {
        int idx = start + i;
        if (idx < N) s += deg[idx];
    }
    part[t] = s;
    __syncthreads();
    for (int off = 1; off < 1024; off <<= 1) {
        int v = (t >= off) ? part[t - off] : 0;
        __syncthreads();
        part[t] += v;
        __syncthreads();
    }
    int run = part[t] - s;  // exclusive prefix of this thread's chunk
    for (int i = 0; i < chunk; i++) {
        int idx = start + i;
        if (idx < N) {
            offs[idx] = run;
            cursor[idx] = run;
            run += deg[idx];
        }
    }
    if (t == 1023) offs[N] = part[1023];
}

__global__ void k_fill(const int* src, const int* dst, int* cursor, int* csr, int E, int N) {
    int e = blockIdx.x * blockDim.x + threadIdx.x;
    if (e < E) {
        int s = src[e], d = dst[e];
        if (s != d) {
            int pos = atomicAdd(&cursor[d], 1);
            csr[pos] = s;
        }
    } else if (e < E + N) {
        int i = e - E;
        int pos = atomicAdd(&cursor[i], 1);
        csr[pos] = i;
    }
}

// ---------------- fold W2 with a_src2/a_dst2 -> [64,8] each ----------------

__global__ __launch_bounds__(512) void k_fold(const float* W2, const float* a_src2,
                                              const float* a_dst2, float* wfold) {
    int u = threadIdx.x;  // 512 = 64 k * 8 h
    int k = u >> 3, h = u & 7;
    float ss = 0.f, sd = 0.f;
    for (int c = 0; c < 128; c++) {
        float w = W2[k * 1024 + h * 128 + c];
        ss += w * a_src2[h * 128 + c];
        sd += w * a_dst2[h * 128 + c];
    }
    wfold[u] = ss;        // w_s2[k*8+h]
    wfold[512 + u] = sd;  // w_d2[k*8+h]
}

// ---------------- layer 1 GEMM: h1 = x @ W1, plus alpha_s1/alpha_d1 ----------------
// 256 threads = 4 waves, 16 nodes/block; each wave owns 4 nodes, lane = column.
// ds_read_b128 feeds 4 FMAs per read (vs 1 before).

__global__ __launch_bounds__(256) void k_gemm1(const float* x, const float* W1,
                                               const float* a_src1, const float* a_dst1,
                                               float* h1, float* as1, float* ad1, int N) {
    __shared__ float xs[16][128];
    int t = threadIdx.x;
    int n0 = blockIdx.x * 16;
#pragma unroll
    for (int i = 0; i < 2; i++) {
        int idx = (t + i * 256) * 4;  // float offset into xs
        int r = idx >> 7, c = idx & 127;
        int n = n0 + r;
        float4 v = make_float4(0.f, 0.f, 0.f, 0.f);
        if (n < N) v = *(const float4*)&x[(size_t)n * 128 + c];
        *(float4*)&xs[r][c] = v;
    }
    __syncthreads();
    int wv = t >> 6, lane = t & 63;
    int m0 = wv * 4;
    float acc[4] = {0.f, 0.f, 0.f, 0.f};
    for (int k0 = 0; k0 < 128; k0 += 4) {
        float w0 = W1[(k0 + 0) * 64 + lane];
        float w1 = W1[(k0 + 1) * 64 + lane];
        float w2 = W1[(k0 + 2) * 64 + lane];
        float w3 = W1[(k0 + 3) * 64 + lane];
#pragma unroll
        for (int mi = 0; mi < 4; mi++) {
            float4 a = *(const float4*)&xs[m0 + mi][k0];
            acc[mi] += a.x * w0 + a.y * w1 + a.z * w2 + a.w * w3;
        }
    }
    float was = a_src1[lane], wad = a_dst1[lane];
#pragma unroll
    for (int mi = 0; mi < 4; mi++) {
        int n = n0 + m0 + mi;
        if (n >= N) break;
        h1[(size_t)n * 64 + lane] = acc[mi];
        float ps = acc[mi] * was, pd = acc[mi] * wad;
        ps += __shfl_xor(ps, 1); ps += __shfl_xor(ps, 2); ps += __shfl_xor(ps, 4);
        pd += __shfl_xor(pd, 1); pd += __shfl_xor(pd, 2); pd += __shfl_xor(pd, 4);
        if ((lane & 7) == 0) {
            as1[n * 8 + (lane >> 3)] = ps;
            ad1[n * 8 + (lane >> 3)] = pd;
        }
    }
}

// ---------------- normalized attention weights (shared by both layers) ----------------

__global__ __launch_bounds__(256) void k_alpha(const int* offs, const int* csr,
                                               const float* as, const float* ad,
                                               float* alpha, int N) {
    int node = blockIdx.x * 4 + (threadIdx.x >> 6);
    if (node >= N) return;
    int lane = threadIdx.x & 63;
    int el = lane >> 3, h = lane & 7;
    float adv = ad[node * 8 + h];
    int beg = offs[node], end = offs[node + 1];
    float m = -1e30f, l = 0.f;
    for (int j0 = beg; j0 < end; j0 += 8) {
        int j = j0 + el;
        float e = -1e30f;
        if (j < end) {
            int s = csr[j];
            float v = as[s * 8 + h] + adv;
            e = LRELU(v);
        }
        float nm = fmaxf(m, e);
        float t1 = l * __expf(m - nm);
        float t2 = (j < end) ? __expf(e - nm) : 0.f;
        l = t1 + t2;
        m = nm;
    }
    for (int off = 8; off < 64; off <<= 1) {
        float m2 = __shfl_xor(m, off);
        float l2 = __shfl_xor(l, off);
        float nm = fmaxf(m, m2);
        l = l * __expf(m - nm) + l2 * __expf(m2 - nm);
        m = nm;
    }
    float inv = 1.f / (l + 1e-16f);
    for (int j0 = beg; j0 < end; j0 += 8) {
        int j = j0 + el;
        if (j < end) {
            int s = csr[j];
            float v = as[s * 8 + h] + adv;
            float e = LRELU(v);
            alpha[(size_t)j * 8 + h] = __expf(e - m) * inv;
        }
    }
}

// ---------------- layer 1 aggregation + bias + ELU + layer-2 alpha fold ----------------

__global__ __launch_bounds__(256) void k_agg1(const int* offs, const int* csr, const float* h1,
                                              const float* alpha, const float* b1,
                                              const float* wfold, float* z, float* as2,
                                              float* ad2, int N) {
    __shared__ float zr[4][64];
    int warp = threadIdx.x >> 6;
    int node = blockIdx.x * 4 + warp;
    int t = threadIdx.x & 63;
    bool valid = node < N;
    float zv = 0.f;
    if (valid) {
        int beg = offs[node], end = offs[node + 1];
        int h = t >> 3;
        float acc = 0.f;
        for (int j = beg; j < end; j++) {
            int s = csr[j];
            float a = alpha[(size_t)j * 8 + h];
            acc += a * h1[(size_t)s * 64 + t];
        }
        float val = acc + b1[t];
        zv = val > 0.f ? val : __expf(val) - 1.f;  // ELU
        z[(size_t)node * 64 + t] = zv;
    }
    zr[warp][t] = zv;
    __syncthreads();
    if (valid && t < 16) {
        int hh = t & 7;
        const float* wf = wfold + (t < 8 ? 0 : 512);
        float s = 0.f;
        for (int k = 0; k < 64; k++) s += zr[warp][k] * wf[k * 8 + hh];
        if (t < 8) as2[node * 8 + hh] = s;
        else       ad2[node * 8 + hh] = s;
    }
}

// ---------------- layer 2 aggregation into agg[N,8,64] (pre-GEMM features) ----------------

__global__ __launch_bounds__(256) void k_agg2(const int* offs, const int* csr, const float* z,
                                              const float* alpha, float* agg, int N) {
    int node = blockIdx.x * 4 + (threadIdx.x >> 6);
    if (node >= N) return;
    int t = threadIdx.x & 63;
    int beg = offs[node], end = offs[node + 1];
    float acc[8] = {0.f, 0.f, 0.f, 0.f, 0.f, 0.f, 0.f, 0.f};
    for (int j = beg; j < end; j++) {
        int s = csr[j];
        float zvv = z[(size_t)s * 64 + t];
        const float4* ap = (const float4*)(alpha + (size_t)j * 8);
        float4 a0 = ap[0], a1 = ap[1];
        acc[0] += a0.x * zvv; acc[1] += a0.y * zvv;
        acc[2] += a0.z * zvv; acc[3] += a0.w * zvv;
        acc[4] += a1.x * zvv; acc[5] += a1.y * zvv;
        acc[6] += a1.z * zvv; acc[7] += a1.w * zvv;
    }
#pragma unroll
    for (int h = 0; h < 8; h++)
        agg[(size_t)node * 512 + h * 64 + t] = acc[h];
}

// ---------------- final per-head GEMM + bias + log_softmax ----------------
// Thread t owns channels 4t..4t+3 (same head). One ds_read_b128 feeds 16 FMAs.

__global__ __launch_bounds__(256) void k_out(const float* agg, const float* W2, const float* b2,
                                             float* out, int N) {
    __shared__ float sa[4096];  // 8 nodes x 512
    __shared__ float red[4][8];
    int t = threadIdx.x;
    int n0 = blockIdx.x * 8;
#pragma unroll
    for (int i = 0; i < 4; i++) {
        int idx = (t + i * 256) * 4;  // float offset, 4096 floats total
        int r = idx >> 9, c = idx & 511;
        int n = n0 + r;
        float4 v = make_float4(0.f, 0.f, 0.f, 0.f);
        if (n < N) v = *(const float4*)&agg[(size_t)n * 512 + c];
        *(float4*)&sa[idx] = v;
    }
    __syncthreads();
    int c0 = t * 4;   // 4 consecutive channels, all in head hh
    int hh = t >> 5;  // (4t) >> 7
    float4 acc[8];
    float4 bb = *(const float4*)&b2[c0];
#pragma unroll
    for (int mi = 0; mi < 8; mi++) acc[mi] = bb;
    for (int k0 = 0; k0 < 64; k0 += 4) {
        float4 w0 = *(const float4*)&W2[(size_t)(k0 + 0) * 1024 + c0];
        float4 w1 = *(const float4*)&W2[(size_t)(k0 + 1) * 1024 + c0];
        float4 w2 = *(const float4*)&W2[(size_t)(k0 + 2) * 1024 + c0];
        float4 w3 = *(const float4*)&W2[(size_t)(k0 + 3) * 1024 + c0];
#pragma unroll
        for (int mi = 0; mi < 8; mi++) {
            float4 a = *(const float4*)&sa[mi * 512 + hh * 64 + k0];
            acc[mi].x += a.x * w0.x + a.y * w1.x + a.z * w2.x + a.w * w3.x;
            acc[mi].y += a.x * w0.y + a.y * w1.y + a.z * w2.y + a.w * w3.y;
            acc[mi].z += a.x * w0.z + a.y * w1.z + a.z * w2.z + a.w * w3.z;
            acc[mi].w += a.x * w0.w + a.y * w1.w + a.z * w2.w + a.w * w3.w;
        }
    }
    // log_softmax over 1024 channels per node
    int wave = t >> 6, lane = t & 63;
    float gmax[8], logZ[8];
#pragma unroll
    for (int mi = 0; mi < 8; mi++) {
        float v = fmaxf(fmaxf(acc[mi].x, acc[mi].y), fmaxf(acc[mi].z, acc[mi].w));
        for (int off = 32; off; off >>= 1) v = fmaxf(v, __shfl_xor(v, off));
        if (lane == 0) red[wave][mi] = v;
    }
    __syncthreads();
#pragma unroll
    for (int mi = 0; mi < 8; mi++)
        gmax[mi] = fmaxf(fmaxf(red[0][mi], red[1][mi]), fmaxf(red[2][mi], red[3][mi]));
    __syncthreads();
#pragma unroll
    for (int mi = 0; mi < 8; mi++) {
        float v = __expf(acc[mi].x - gmax[mi]) + __expf(acc[mi].y - gmax[mi]) +
                  __expf(acc[mi].z - gmax[mi]) + __expf(acc[mi].w - gmax[mi]);
        for (int off = 32; off; off >>= 1) v += __shfl_xor(v, off);
        if (lane == 0) red[wave][mi] = v;
    }
    __syncthreads();
#pragma unroll
    for (int mi = 0; mi < 8; mi++) {
        float gs = red[0][mi] + red[1][mi] + red[2][mi] + red[3][mi];
        logZ[mi] = gmax[mi] + __logf(gs);
    }
#pragma unroll
    for (int mi = 0; mi < 8; mi++) {
        int n = n0 + mi;
        if (n >= N) continue;
        float4 o;
        o.x = acc[mi].x - logZ[mi];
        o.y = acc[mi].y - logZ[mi];
        o.z = acc[mi].z - logZ[mi];
        o.w = acc[mi].w - logZ[mi];
        *(float4*)&out[(size_t)n * 1024 + c0] = o;
    }
}

// ---------------- launch ----------------

extern "C" void kernel_launch(void* const* d_in, const int* in_sizes, int n_in,
                              void* d_out, int out_size, void* d_ws, size_t ws_size,
                              hipStream_t stream) {
    const float* x      = (const float*)d_in[0];
    const int*   ei     = (const int*)d_in[1];
    const float* W1     = (const float*)d_in[2];
    const float* a_src1 = (const float*)d_in[3];
    const float* a_dst1 = (const float*)d_in[4];
    const float* b1     = (const float*)d_in[5];
    const float* W2     = (const float*)d_in[6];
    const float* a_src2 = (const float*)d_in[7];
    const float* a_dst2 = (const float*)d_in[8];
    const float* b2     = (const float*)d_in[9];
    float* out = (float*)d_out;

    int N = in_sizes[0] / 128;
    int E = in_sizes[1] / 2;
    const int* src = ei;
    const int* dst = ei + E;

    // workspace carve (256B-aligned regions)
    char* p = (char*)d_ws;
    auto carve = [&](size_t bytes) {
        void* r = (void*)p;
        p += (bytes + 255) & ~(size_t)255;
        return r;
    };
    int*   deg    = (int*)carve((size_t)N * 4);
    int*   offs   = (int*)carve((size_t)(N + 1) * 4);
    int*   cursor = (int*)carve((size_t)N * 4);
    int*   csr    = (int*)carve((size_t)(E + N) * 4);
    float* h1     = (float*)carve((size_t)N * 64 * 4);
    float* as1    = (float*)carve((size_t)N * 8 * 4);
    float* ad1    = (float*)carve((size_t)N * 8 * 4);
    float* z      = (float*)carve((size_t)N * 64 * 4);
    float* as2    = (float*)carve((size_t)N * 8 * 4);
    float* ad2    = (float*)carve((size_t)N * 8 * 4);
    float* wfold  = (float*)carve((size_t)1024 * 4);
    float* alpha  = (float*)carve((size_t)(E + N) * 8 * 4);  // reused by both layers
    float* agg    = (float*)carve((size_t)N * 512 * 4);

    int nb4 = (N + 3) / 4;

    // CSR build
    k_deg_init<<<(N + 255) / 256, 256, 0, stream>>>(deg, N);
    k_hist<<<(E + 255) / 256, 256, 0, stream>>>(src, dst, deg, E);
    k_scan<<<1, 1024, 0, stream>>>(deg, offs, cursor, N);
    k_fill<<<(E + N + 255) / 256, 256, 0, stream>>>(src, dst, cursor, csr, E, N);

    // fold W2 with attention vectors
    k_fold<<<1, 512, 0, stream>>>(W2, a_src2, a_dst2, wfold);

    // layer 1
    k_gemm1<<<(N + 15) / 16, 256, 0, stream>>>(x, W1, a_src1, a_dst1, h1, as1, ad1, N);
    k_alpha<<<nb4, 256, 0, stream>>>(offs, csr, as1, ad1, alpha, N);
    k_agg1<<<nb4, 256, 0, stream>>>(offs, csr, h1, alpha, b1, wfold, z, as2, ad2, N);

    // layer 2
    k_alpha<<<nb4, 256, 0, stream>>>(offs, csr, as2, ad2, alpha, N);
    k_agg2<<<nb4, 256, 0, stream>>>(offs, csr, z, alpha, agg, N);
    k_out<<<(N + 7) / 8, 256, 0, stream>>>(agg, W2, b2, out, N);
}

// Round 4
// 226.681 us; speedup vs baseline: 1.2399x; 1.2399x over previous
//
#include <hip/hip_runtime.h>
#include <cstddef>
#include <cstdint>

#define LRELU(v) ((v) > 0.f ? (v) : 0.2f * (v))

// ================= K1: fused gemm1 + fold(W2,a2) + deg-init =================
// blocks [0,GB): h1 = x@W1 (+as1/ad1);  [GB,GB+64): wfold;  rest: deg[i]=1.

__global__ __launch_bounds__(256) void k_front(const float* __restrict__ x,
                                               const float* __restrict__ W1,
                                               const float* __restrict__ a_src1,
                                               const float* __restrict__ a_dst1,
                                               const float* __restrict__ W2,
                                               const float* __restrict__ a_src2,
                                               const float* __restrict__ a_dst2,
                                               float* h1, float* as1, float* ad1,
                                               float* wfold, int* deg, int N, int GB) {
    int t = threadIdx.x;
    int b = blockIdx.x;
    if (b < GB) {
        // ---- gemm1: 16 nodes/block, 4 waves, wave owns 4 nodes, lane = column ----
        __shared__ float xs[16][128];
        int n0 = b * 16;
#pragma unroll
        for (int i = 0; i < 2; i++) {
            int idx = (t + i * 256) * 4;
            int r = idx >> 7, c = idx & 127;
            int n = n0 + r;
            float4 v = make_float4(0.f, 0.f, 0.f, 0.f);
            if (n < N) v = *(const float4*)&x[(size_t)n * 128 + c];
            *(float4*)&xs[r][c] = v;
        }
        __syncthreads();
        int wv = t >> 6, lane = t & 63;
        int m0 = wv * 4;
        float acc[4] = {0.f, 0.f, 0.f, 0.f};
        for (int k0 = 0; k0 < 128; k0 += 4) {
            float w0 = W1[(k0 + 0) * 64 + lane];
            float w1 = W1[(k0 + 1) * 64 + lane];
            float w2 = W1[(k0 + 2) * 64 + lane];
            float w3 = W1[(k0 + 3) * 64 + lane];
#pragma unroll
            for (int mi = 0; mi < 4; mi++) {
                float4 a = *(const float4*)&xs[m0 + mi][k0];
                acc[mi] += a.x * w0 + a.y * w1 + a.z * w2 + a.w * w3;
            }
        }
        float was = a_src1[lane], wad = a_dst1[lane];
#pragma unroll
        for (int mi = 0; mi < 4; mi++) {
            int n = n0 + m0 + mi;
            if (n >= N) break;
            h1[(size_t)n * 64 + lane] = acc[mi];
            float ps = acc[mi] * was, pd = acc[mi] * wad;
            ps += __shfl_xor(ps, 1); ps += __shfl_xor(ps, 2); ps += __shfl_xor(ps, 4);
            pd += __shfl_xor(pd, 1); pd += __shfl_xor(pd, 2); pd += __shfl_xor(pd, 4);
            if ((lane & 7) == 0) {
                as1[n * 8 + (lane >> 3)] = ps;
                ad1[n * 8 + (lane >> 3)] = pd;
            }
        }
    } else if (b < GB + 64) {
        // ---- fold: block per k-row of W2; coalesced float4; 32-lane head groups ----
        int k = b - GB;
        int c0 = t * 4;
        int h = t >> 5;
        float4 w = *(const float4*)&W2[(size_t)k * 1024 + c0];
        float4 s4 = *(const float4*)&a_src2[c0];
        float4 d4 = *(const float4*)&a_dst2[c0];
        float ss = w.x * s4.x + w.y * s4.y + w.z * s4.z + w.w * s4.w;
        float sd = w.x * d4.x + w.y * d4.y + w.z * d4.z + w.w * d4.w;
#pragma unroll
        for (int off = 1; off <= 16; off <<= 1) {
            ss += __shfl_xor(ss, off);
            sd += __shfl_xor(sd, off);
        }
        if ((t & 31) == 0) {
            wfold[k * 8 + h] = ss;
            wfold[512 + k * 8 + h] = sd;
        }
    } else {
        int i = (b - GB - 64) * 256 + t;
        if (i < N) deg[i] = 1;  // self-loop
    }
}

// ================= CSR build =================

__global__ void k_hist(const int* src, const int* dst, int* deg, int E) {
    int e = blockIdx.x * blockDim.x + threadIdx.x;
    if (e < E) {
        int s = src[e], d = dst[e];
        if (s != d) atomicAdd(&deg[d], 1);
    }
}

__global__ __launch_bounds__(1024) void k_scan(const int* deg, int* offs, int* cursor, int N) {
    __shared__ int part[1024];
    int t = threadIdx.x;
    int chunk = (N + 1023) >> 10;
    int start = t * chunk;
    int s = 0;
    for (int i = 0; i < chunk; i++) {
        int idx = start + i;
        if (idx < N) s += deg[idx];
    }
    part[t] = s;
    __syncthreads();
    for (int off = 1; off < 1024; off <<= 1) {
        int v = (t >= off) ? part[t - off] : 0;
        __syncthreads();
        part[t] += v;
        __syncthreads();
    }
    int run = part[t] - s;
    for (int i = 0; i < chunk; i++) {
        int idx = start + i;
        if (idx < N) {
            offs[idx] = run;
            cursor[idx] = run;
            run += deg[idx];
        }
    }
    if (t == 1023) offs[N] = part[1023];
}

__global__ void k_fill(const int* src, const int* dst, int* cursor, int* csr, int E, int N) {
    int e = blockIdx.x * blockDim.x + threadIdx.x;
    if (e < E) {
        int s = src[e], d = dst[e];
        if (s != d) {
            int pos = atomicAdd(&cursor[d], 1);
            csr[pos] = s;
        }
    } else if (e < E + N) {
        int i = e - E;
        int pos = atomicAdd(&cursor[i], 1);
        csr[pos] = i;
    }
}

// ================= fused attention+aggregation, layer 1 =================
// One wave per dst node. Phase A: online-softmax alpha into per-wave LDS.
// Phase B: aggregate h1, bias+ELU -> z, then wfold dot -> as2/ad2.

__global__ __launch_bounds__(256) void k_attn1(const int* offs, const int* csr,
                                               const float* __restrict__ h1,
                                               const float* __restrict__ as1,
                                               const float* __restrict__ ad1,
                                               const float* __restrict__ b1,
                                               const float* __restrict__ wfold,
                                               float* z, float* as2, float* ad2, int N) {
    __shared__ float al[4][512];  // 64 edges x 8 heads per wave
    __shared__ int   sc[4][64];
    __shared__ float zr[4][64];
    int w = threadIdx.x >> 6, lane = threadIdx.x & 63;
    int node = blockIdx.x * 4 + w;
    if (node >= N) return;
    int el = lane >> 3, h = lane & 7;
    int beg = offs[node], end = offs[node + 1];
    int deg = end - beg;
    float adv = ad1[node * 8 + h];
    float m = -1e30f, l = 0.f;
    for (int it = 0; it * 8 < deg; it++) {
        int j = beg + it * 8 + el;
        float e = -1e30f;
        int s = 0;
        if (j < end) {
            s = csr[j];
            float v = as1[s * 8 + h] + adv;
            e = LRELU(v);
        }
        if (it < 8) {
            al[w][it * 64 + lane] = e;  // linear: no bank conflicts
            if (h == 0 && j < end) sc[w][it * 8 + el] = s;
        }
        float nm = fmaxf(m, e);
        l = l * __expf(m - nm) + ((j < end) ? __expf(e - nm) : 0.f);
        m = nm;
    }
#pragma unroll
    for (int off = 8; off < 64; off <<= 1) {
        float m2 = __shfl_xor(m, off), l2 = __shfl_xor(l, off);
        float nm = fmaxf(m, m2);
        l = l * __expf(m - nm) + l2 * __expf(m2 - nm);
        m = nm;
    }
    float inv = 1.f / (l + 1e-16f);
    for (int it = 0; it < 8 && it * 8 < deg; it++) {
        int idx = it * 64 + lane;
        al[w][idx] = __expf(al[w][idx] - m) * inv;
    }
    // ---- phase B: lane = channel, head hb ----
    int hb = lane >> 3;
    float mB   = __shfl(m, hb);
    float invB = __shfl(inv, hb);
    float advB = __shfl(adv, hb);
    float acc = 0.f;
    for (int j = beg; j < end; j++) {
        int e0 = j - beg;
        float a;
        int s;
        if (e0 < 64) {
            a = al[w][e0 * 8 + hb];
            s = sc[w][e0];
        } else {  // overflow: recompute (deg>64 is rare)
            s = csr[j];
            float v = as1[s * 8 + hb] + advB;
            a = __expf(LRELU(v) - mB) * invB;
        }
        acc += a * h1[(size_t)s * 64 + lane];
    }
    float val = acc + b1[lane];
    float zv = val > 0.f ? val : __expf(val) - 1.f;  // ELU
    z[(size_t)node * 64 + lane] = zv;
    zr[w][lane] = zv;
    if (lane < 16) {
        int hh = lane & 7;
        const float* wf = wfold + (lane < 8 ? 0 : 512);
        float sdot = 0.f;
        for (int k = 0; k < 64; k++) sdot += zr[w][k] * wf[k * 8 + hh];
        if (lane < 8) as2[node * 8 + hh] = sdot;
        else          ad2[node * 8 + hh] = sdot;
    }
}

// ================= fused attention+aggregation, layer 2 =================
// Phase B: lane = channel (64), all 8 heads accumulated -> agg[N,8,64].

__global__ __launch_bounds__(256) void k_attn2(const int* offs, const int* csr,
                                               const float* __restrict__ zt,
                                               const float* __restrict__ as2,
                                               const float* __restrict__ ad2,
                                               float* agg, int N) {
    __shared__ float al[4][512];
    __shared__ int   sc[4][64];
    int w = threadIdx.x >> 6, lane = threadIdx.x & 63;
    int node = blockIdx.x * 4 + w;
    if (node >= N) return;
    int el = lane >> 3, h = lane & 7;
    int beg = offs[node], end = offs[node + 1];
    int deg = end - beg;
    float adv = ad2[node * 8 + h];
    float m = -1e30f, l = 0.f;
    for (int it = 0; it * 8 < deg; it++) {
        int j = beg + it * 8 + el;
        float e = -1e30f;
        int s = 0;
        if (j < end) {
            s = csr[j];
            float v = as2[s * 8 + h] + adv;
            e = LRELU(v);
        }
        if (it < 8) {
            al[w][it * 64 + lane] = e;
            if (h == 0 && j < end) sc[w][it * 8 + el] = s;
        }
        float nm = fmaxf(m, e);
        l = l * __expf(m - nm) + ((j < end) ? __expf(e - nm) : 0.f);
        m = nm;
    }
#pragma unroll
    for (int off = 8; off < 64; off <<= 1) {
        float m2 = __shfl_xor(m, off), l2 = __shfl_xor(l, off);
        float nm = fmaxf(m, m2);
        l = l * __expf(m - nm) + l2 * __expf(m2 - nm);
        m = nm;
    }
    float inv = 1.f / (l + 1e-16f);
    for (int it = 0; it < 8 && it * 8 < deg; it++) {
        int idx = it * 64 + lane;
        al[w][idx] = __expf(al[w][idx] - m) * inv;
    }
    float mH[8], invH[8], advH[8];
#pragma unroll
    for (int hh = 0; hh < 8; hh++) {
        mH[hh] = __shfl(m, hh);
        invH[hh] = __shfl(inv, hh);
        advH[hh] = __shfl(adv, hh);
    }
    float acc[8] = {0.f, 0.f, 0.f, 0.f, 0.f, 0.f, 0.f, 0.f};
    for (int j = beg; j < end; j++) {
        int e0 = j - beg;
        float a[8];
        int s;
        if (e0 < 64) {
            float4 a0 = *(const float4*)&al[w][e0 * 8];
            float4 a1 = *(const float4*)&al[w][e0 * 8 + 4];
            a[0] = a0.x; a[1] = a0.y; a[2] = a0.z; a[3] = a0.w;
            a[4] = a1.x; a[5] = a1.y; a[6] = a1.z; a[7] = a1.w;
            s = sc[w][e0];
        } else {
            s = csr[j];
#pragma unroll
            for (int hh = 0; hh < 8; hh++) {
                float v = as2[s * 8 + hh] + advH[hh];
                a[hh] = __expf(LRELU(v) - mH[hh]) * invH[hh];
            }
        }
        float zvv = zt[(size_t)s * 64 + lane];
#pragma unroll
        for (int hh = 0; hh < 8; hh++) acc[hh] += a[hh] * zvv;
    }
#pragma unroll
    for (int hh = 0; hh < 8; hh++)
        agg[(size_t)node * 512 + hh * 64 + lane] = acc[hh];
}

// ================= final per-head GEMM + bias + log_softmax =================

__global__ __launch_bounds__(256) void k_out(const float* __restrict__ agg,
                                             const float* __restrict__ W2,
                                             const float* __restrict__ b2,
                                             float* out, int N) {
    __shared__ float sa[4096];
    __shared__ float red[4][8];
    int t = threadIdx.x;
    int n0 = blockIdx.x * 8;
#pragma unroll
    for (int i = 0; i < 4; i++) {
        int idx = (t + i * 256) * 4;
        int r = idx >> 9, c = idx & 511;
        int n = n0 + r;
        float4 v = make_float4(0.f, 0.f, 0.f, 0.f);
        if (n < N) v = *(const float4*)&agg[(size_t)n * 512 + c];
        *(float4*)&sa[idx] = v;
    }
    __syncthreads();
    int c0 = t * 4;
    int hh = t >> 5;
    float4 acc[8];
    float4 bb = *(const float4*)&b2[c0];
#pragma unroll
    for (int mi = 0; mi < 8; mi++) acc[mi] = bb;
    for (int k0 = 0; k0 < 64; k0 += 4) {
        float4 w0 = *(const float4*)&W2[(size_t)(k0 + 0) * 1024 + c0];
        float4 w1 = *(const float4*)&W2[(size_t)(k0 + 1) * 1024 + c0];
        float4 w2 = *(const float4*)&W2[(size_t)(k0 + 2) * 1024 + c0];
        float4 w3 = *(const float4*)&W2[(size_t)(k0 + 3) * 1024 + c0];
#pragma unroll
        for (int mi = 0; mi < 8; mi++) {
            float4 a = *(const float4*)&sa[mi * 512 + hh * 64 + k0];
            acc[mi].x += a.x * w0.x + a.y * w1.x + a.z * w2.x + a.w * w3.x;
            acc[mi].y += a.x * w0.y + a.y * w1.y + a.z * w2.y + a.w * w3.y;
            acc[mi].z += a.x * w0.z + a.y * w1.z + a.z * w2.z + a.w * w3.z;
            acc[mi].w += a.x * w0.w + a.y * w1.w + a.z * w2.w + a.w * w3.w;
        }
    }
    int wave = t >> 6, lane = t & 63;
    float gmax[8], logZ[8];
#pragma unroll
    for (int mi = 0; mi < 8; mi++) {
        float v = fmaxf(fmaxf(acc[mi].x, acc[mi].y), fmaxf(acc[mi].z, acc[mi].w));
        for (int off = 32; off; off >>= 1) v = fmaxf(v, __shfl_xor(v, off));
        if (lane == 0) red[wave][mi] = v;
    }
    __syncthreads();
#pragma unroll
    for (int mi = 0; mi < 8; mi++)
        gmax[mi] = fmaxf(fmaxf(red[0][mi], red[1][mi]), fmaxf(red[2][mi], red[3][mi]));
    __syncthreads();
#pragma unroll
    for (int mi = 0; mi < 8; mi++) {
        float v = __expf(acc[mi].x - gmax[mi]) + __expf(acc[mi].y - gmax[mi]) +
                  __expf(acc[mi].z - gmax[mi]) + __expf(acc[mi].w - gmax[mi]);
        for (int off = 32; off; off >>= 1) v += __shfl_xor(v, off);
        if (lane == 0) red[wave][mi] = v;
    }
    __syncthreads();
#pragma unroll
    for (int mi = 0; mi < 8; mi++) {
        float gs = red[0][mi] + red[1][mi] + red[2][mi] + red[3][mi];
        logZ[mi] = gmax[mi] + __logf(gs);
    }
#pragma unroll
    for (int mi = 0; mi < 8; mi++) {
        int n = n0 + mi;
        if (n >= N) continue;
        float4 o;
        o.x = acc[mi].x - logZ[mi];
        o.y = acc[mi].y - logZ[mi];
        o.z = acc[mi].z - logZ[mi];
        o.w = acc[mi].w - logZ[mi];
        *(float4*)&out[(size_t)n * 1024 + c0] = o;
    }
}

// ================= launch =================

extern "C" void kernel_launch(void* const* d_in, const int* in_sizes, int n_in,
                              void* d_out, int out_size, void* d_ws, size_t ws_size,
                              hipStream_t stream) {
    const float* x      = (const float*)d_in[0];
    const int*   ei     = (const int*)d_in[1];
    const float* W1     = (const float*)d_in[2];
    const float* a_src1 = (const float*)d_in[3];
    const float* a_dst1 = (const float*)d_in[4];
    const float* b1     = (const float*)d_in[5];
    const float* W2     = (const float*)d_in[6];
    const float* a_src2 = (const float*)d_in[7];
    const float* a_dst2 = (const float*)d_in[8];
    const float* b2     = (const float*)d_in[9];
    float* out = (float*)d_out;

    int N = in_sizes[0] / 128;
    int E = in_sizes[1] / 2;
    const int* src = ei;
    const int* dst = ei + E;

    char* p = (char*)d_ws;
    auto carve = [&](size_t bytes) {
        void* r = (void*)p;
        p += (bytes + 255) & ~(size_t)255;
        return r;
    };
    int*   deg    = (int*)carve((size_t)N * 4);
    int*   offs   = (int*)carve((size_t)(N + 1) * 4);
    int*   cursor = (int*)carve((size_t)N * 4);
    int*   csr    = (int*)carve((size_t)(E + N) * 4);
    float* h1     = (float*)carve((size_t)N * 64 * 4);
    float* as1    = (float*)carve((size_t)N * 8 * 4);
    float* ad1    = (float*)carve((size_t)N * 8 * 4);
    float* z      = (float*)carve((size_t)N * 64 * 4);
    float* as2    = (float*)carve((size_t)N * 8 * 4);
    float* ad2    = (float*)carve((size_t)N * 8 * 4);
    float* wfold  = (float*)carve((size_t)1024 * 4);
    float* agg    = (float*)carve((size_t)N * 512 * 4);

    int GB = (N + 15) / 16;                 // gemm1 blocks
    int DB = (N + 255) / 256;               // deg-init blocks
    int nb4 = (N + 3) / 4;

    // K1: gemm1 + fold + deg-init (independent work, one dispatch)
    k_front<<<GB + 64 + DB, 256, 0, stream>>>(x, W1, a_src1, a_dst1, W2, a_src2, a_dst2,
                                              h1, as1, ad1, wfold, deg, N, GB);
    // CSR build
    k_hist<<<(E + 255) / 256, 256, 0, stream>>>(src, dst, deg, E);
    k_scan<<<1, 1024, 0, stream>>>(deg, offs, cursor, N);
    k_fill<<<(E + N + 255) / 256, 256, 0, stream>>>(src, dst, cursor, csr, E, N);
    // layer 1 (fused alpha+agg)
    k_attn1<<<nb4, 256, 0, stream>>>(offs, csr, h1, as1, ad1, b1, wfold, z, as2, ad2, N);
    // layer 2 (fused alpha+agg)
    k_attn2<<<nb4, 256, 0, stream>>>(offs, csr, z, as2, ad2, agg, N);
    // output GEMM + log_softmax
    k_out<<<(N + 7) / 8, 256, 0, stream>>>(agg, W2, b2, out, N);
}